// Round 17
// baseline (112.395 us; speedup 1.0000x reference)
//
#include <hip/hip_runtime.h>
#include <hip/hip_bf16.h>
#include <hip/hip_fp16.h>

#define BATCH 128
#define NPTS  2048
#define NDIM  3
#define NPROJ 100
#define NTH   128   // 2 waves per block: wave 0 sorts P, wave 1 sorts Q
#define NREG  16    // 16 packed regs = 32 x 16-bit keys per thread

typedef unsigned int u32;
typedef _Float16 h2_t __attribute__((ext_vector_type(2)));
typedef unsigned short u16x2 __attribute__((ext_vector_type(2)));

// Packed 2x16-bit unsigned min/max -> v_pk_min_u16 / v_pk_max_u16.
__device__ __forceinline__ u32 pmin(u32 a, u32 b) {
#if __has_builtin(__builtin_elementwise_min)
  return __builtin_bit_cast(u32, __builtin_elementwise_min(
      __builtin_bit_cast(u16x2, a), __builtin_bit_cast(u16x2, b)));
#else
  u32 d; asm("v_pk_min_u16 %0, %1, %2" : "=v"(d) : "v"(a), "v"(b)); return d;
#endif
}
__device__ __forceinline__ u32 pmax(u32 a, u32 b) {
#if __has_builtin(__builtin_elementwise_max)
  return __builtin_bit_cast(u32, __builtin_elementwise_max(
      __builtin_bit_cast(u16x2, a), __builtin_bit_cast(u16x2, b)));
#else
  u32 d; asm("v_pk_max_u16 %0, %1, %2" : "=v"(d) : "v"(a), "v"(b)); return d;
#endif
}

// Pack two f32 -> one u32 of two order-preserving f16 keys (RTZ, monotone).
__device__ __forceinline__ u32 packkey(float lo, float hi) {
  const u32 h2 = __builtin_bit_cast(u32, __builtin_amdgcn_cvt_pkrtz(lo, hi));
  const u32 t = (h2 & 0x80008000u) >> 15;
  return h2 ^ ((t * 0x7FFFu) | 0x80008000u);
}
// Inverse: packed key -> two f32.
__device__ __forceinline__ void unpackkey(u32 k, float& lo, float& hi) {
  const u32 t = ((~k) & 0x80008000u) >> 15;
  const u32 h2 = k ^ ((t * 0x7FFFu) | 0x80008000u);
  const h2_t h = __builtin_bit_cast(h2_t, h2);
  lo = (float)h.x;
  hi = (float)h.y;
}

// Cross-lane xor shuffle: DPP where an exact form exists (VALU), else DS.
// (Mask 4 is handled by the dedicated dual-DPP lanex4 below.)
template<int M>
__device__ __forceinline__ u32 shuf(u32 v, int a63) {
  const int x = (int)v;
  int r;
  if constexpr (M == 1)       r = __builtin_amdgcn_mov_dpp(x, 0xB1, 0xF, 0xF, true);   // quad [1,0,3,2]
  else if constexpr (M == 2)  r = __builtin_amdgcn_mov_dpp(x, 0x4E, 0xF, 0xF, true);   // quad [2,3,0,1]
  else if constexpr (M == 3)  r = __builtin_amdgcn_mov_dpp(x, 0x1B, 0xF, 0xF, true);   // quad [3,2,1,0]
  else if constexpr (M == 7)  r = __builtin_amdgcn_mov_dpp(x, 0x141, 0xF, 0xF, true);  // row_half_mirror
  else if constexpr (M == 8)  r = __builtin_amdgcn_mov_dpp(x, 0x128, 0xF, 0xF, true);  // row_ror:8
  else if constexpr (M == 15) r = __builtin_amdgcn_mov_dpp(x, 0x140, 0xF, 0xF, true);  // row_mirror
  else if constexpr (M == 63) r = __builtin_amdgcn_ds_bpermute(a63, x);
  else                        r = __builtin_amdgcn_ds_swizzle(x, (M << 10) | 0x1F);    // 31
  return (u32)r;
}

// Compare-exchange on two packed regs (min to first).
__device__ __forceinline__ void ce(u32& a, u32& b) {
  const u32 mn = pmin(a, b), mx = pmax(a, b);
  a = mn;
  b = mx;
}

// Batcher odd-even mergesort over the 16 regs (63 CEs); compile-time indices.
template<int I, int R, int END, int M>
__device__ __forceinline__ void oem_chain(u32 v[NREG]) {
  if constexpr (I + R < END) {
    ce(v[I], v[I + R]);
    oem_chain<I + M, R, END, M>(v);
  }
}
template<int LO, int R, int N>
__device__ __forceinline__ void oem_merge(u32 v[NREG]) {
  constexpr int M = R * 2;
  if constexpr (M < N) {
    oem_merge<LO, M, N>(v);
    oem_merge<LO + R, M, N>(v);
    oem_chain<LO + R, R, LO + N, M>(v);
  } else {
    ce(v[LO], v[LO + R]);
  }
}
template<int LO, int N>
__device__ __forceinline__ void oem_sort(u32 v[NREG]) {
  if constexpr (N > 1) {
    constexpr int M = N / 2;
    oem_sort<LO, M>(v);
    oem_sort<LO + M, M>(v);
    oem_merge<LO, 1, N>(v);
  }
}

// Reg-bit xor CE (bitonic merge substep, uniform direction).
template<int J>
__device__ __forceinline__ void regx(u32 v[NREG]) {
#pragma unroll
  for (int s = 0; s < NREG; ++s) {
    if ((s & J) == 0) {
      const u32 a = v[s], b = v[s | J];
      v[s] = pmin(a, b);
      v[s | J] = pmax(a, b);
    }
  }
}

// Lane-space reversal CE: partner lane^M, regs reversed; lane&HB==0 keeps min.
template<int M, int HB>
__device__ __forceinline__ void lanerev(u32 v[NREG], const int lane, const int a63) {
  u32 o[NREG];
#pragma unroll
  for (int r = 0; r < NREG; ++r) o[r] = shuf<M>(v[NREG - 1 - r], a63);
  if (lane & HB) {
#pragma unroll
    for (int r = 0; r < NREG; ++r) v[r] = pmax(v[r], o[r]);
  } else {
#pragma unroll
    for (int r = 0; r < NREG; ++r) v[r] = pmin(v[r], o[r]);
  }
}

// Lane-space xor CE at lane mask M (exact shuffles).
template<int M>
__device__ __forceinline__ void lanex(u32 v[NREG], const int lane, const int a63) {
  u32 o[NREG];
#pragma unroll
  for (int r = 0; r < NREG; ++r) o[r] = shuf<M>(v[r], a63);
  if (lane & M) {
#pragma unroll
    for (int r = 0; r < NREG; ++r) v[r] = pmax(v[r], o[r]);
  } else {
#pragma unroll
    for (int r = 0; r < NREG; ++r) v[r] = pmin(v[r], o[r]);
  }
}

// Lane-space xor CE at mask 4 on the VALU pipe. GCN DPP convention (per the
// canonical prefix-sum idiom "v_add row_shr:1 = add from lane below"):
//   row_shr:N -> dest i <- src i-N (lanes 0..N-1 vacated)
//   row_shl:N -> dest i <- src i+N (upper N lanes vacated)
// Lanes with bit2 SET need partner lane-4 -> row_shr:4 (vacated 0-3 unused
// there); lanes with bit2 CLEAR need lane+4 -> row_shl:4 (vacated 12-15
// unused). R16 had the two swapped -> bound_ctrl zeros -> key 0 -> f16 NaN.
__device__ __forceinline__ void lanex4(u32 v[NREG], const int lane) {
#pragma unroll
  for (int c = 0; c < 2; ++c) {
    u32 oshl[8], oshr[8];
#pragma unroll
    for (int r = 0; r < 8; ++r) {
      oshl[r] = (u32)__builtin_amdgcn_mov_dpp((int)v[c * 8 + r], 0x104, 0xF, 0xF, true); // row_shl:4
      oshr[r] = (u32)__builtin_amdgcn_mov_dpp((int)v[c * 8 + r], 0x114, 0xF, 0xF, true); // row_shr:4
    }
    if (lane & 4) {
#pragma unroll
      for (int r = 0; r < 8; ++r) v[c * 8 + r] = pmax(v[c * 8 + r], oshr[r]);
    } else {
#pragma unroll
      for (int r = 0; r < 8; ++r) v[c * 8 + r] = pmin(v[c * 8 + r], oshl[r]);
    }
  }
}

// Lane-space xor CE at mask 16/32 via permlane swap (unordered pair, VALU).
template<int HB>
__device__ __forceinline__ void lanepair(u32 v[NREG], const int lane) {
  u32 a[NREG], o[NREG];
#pragma unroll
  for (int r = 0; r < NREG; ++r) {
    if constexpr (HB == 16) {
#if __has_builtin(__builtin_amdgcn_permlane16_swap)
      auto p = __builtin_amdgcn_permlane16_swap((int)v[r], (int)v[r], false, false);
      a[r] = (u32)p[0]; o[r] = (u32)p[1];
#else
      a[r] = v[r];
      o[r] = (u32)__builtin_amdgcn_ds_swizzle((int)v[r], (16 << 10) | 0x1F);
#endif
    } else {
#if __has_builtin(__builtin_amdgcn_permlane32_swap)
      auto p = __builtin_amdgcn_permlane32_swap((int)v[r], (int)v[r], false, false);
      a[r] = (u32)p[0]; o[r] = (u32)p[1];
#else
      a[r] = v[r];
      o[r] = (u32)__builtin_amdgcn_ds_bpermute(((lane ^ 32) << 2), (int)v[r]);
#endif
    }
  }
  if (lane & HB) {
#pragma unroll
    for (int r = 0; r < NREG; ++r) v[r] = pmax(a[r], o[r]);
  } else {
#pragma unroll
    for (int r = 0; r < NREG; ++r) v[r] = pmin(a[r], o[r]);
  }
}

// K=2048 reversal: flips half bit + lane^63 + reg reversal; partner arrives
// half-swapped (alignbit rotate 16); lo half keeps min, hi keeps max.
__device__ __forceinline__ void halfrev(u32 v[NREG], const int a63, const u32 hm) {
  u32 o[NREG];
#pragma unroll
  for (int r = 0; r < NREG; ++r) o[r] = shuf<63>(v[NREG - 1 - r], a63);
#pragma unroll
  for (int r = 0; r < NREG; ++r) {
    u32 osw;
    asm("v_alignbit_b32 %0, %1, %1, 16" : "=v"(osw) : "v"(o[r]));
    const u32 t1 = pmin(v[r], osw);
    const u32 t2 = pmax(v[r], osw);
    asm("v_bfi_b32 %0, %1, %2, %3" : "=v"(v[r]) : "v"(hm), "v"(t2), "v"(t1));
  }
}

#define REGX4 regx<8>(v); regx<4>(v); regx<2>(v); regx<1>(v)

// ---------------------------------------------------------------------------
// One 128-thread block per (b, l). Wave 0: P, wave 1: Q. 2048 f16 keys per
// wave packed 2-per-register; XCD-bijective swizzle for L2 reuse.
// ---------------------------------------------------------------------------
__global__ __launch_bounds__(NTH) void swd_sort_kernel(
    const float* __restrict__ P, const float* __restrict__ Q,
    const float* __restrict__ proj, float* __restrict__ partial) {
  __shared__ float sj[64 * 33];
  // 12800 blocks, 8 XCDs, 12800%8==0: xcd = bid%8 owns pairs [xcd*1600, ..)
  const int pair = (blockIdx.x & 7) * (BATCH * NPROJ / 8) + (blockIdx.x >> 3);
  const int b = pair / NPROJ;
  const int l = pair - b * NPROJ;
  const int wid  = threadIdx.x >> 6;
  const int lane = threadIdx.x & 63;
  const int a63 = ((lane ^ 63) << 2);
  const u32 hm = 0xFFFF0000u;

  const float d0 = proj[b * NDIM * NPROJ + l];
  const float d1 = proj[b * NDIM * NPROJ + NPROJ + l];
  const float d2 = proj[b * NDIM * NPROJ + 2 * NPROJ + l];

  const float* __restrict__ src = wid ? Q : P;
  const float4* base = reinterpret_cast<const float4*>(src + (size_t)b * NPTS * NDIM);
  const float4* SA = base + lane * 12;        // points lane*16 .. +15  (half 0)
  const float4* SB = base + 768 + lane * 12;  // points 1024+lane*16 ..(half 1)

  float pl[NREG], ph[NREG];
#pragma unroll
  for (int c = 0; c < 4; ++c) {  // 3 float4 = 4 points
    const float4 x = SA[c * 3 + 0], y = SA[c * 3 + 1], z = SA[c * 3 + 2];
    pl[c * 4 + 0] = x.x * d0 + x.y * d1 + x.z * d2;
    pl[c * 4 + 1] = x.w * d0 + y.x * d1 + y.y * d2;
    pl[c * 4 + 2] = y.z * d0 + y.w * d1 + z.x * d2;
    pl[c * 4 + 3] = z.y * d0 + z.z * d1 + z.w * d2;
  }
#pragma unroll
  for (int c = 0; c < 4; ++c) {
    const float4 x = SB[c * 3 + 0], y = SB[c * 3 + 1], z = SB[c * 3 + 2];
    ph[c * 4 + 0] = x.x * d0 + x.y * d1 + x.z * d2;
    ph[c * 4 + 1] = x.w * d0 + y.x * d1 + y.y * d2;
    ph[c * 4 + 2] = y.z * d0 + y.w * d1 + z.x * d2;
    ph[c * 4 + 3] = z.y * d0 + z.z * d1 + z.w * d2;
  }

  u32 v[NREG];
#pragma unroll
  for (int r = 0; r < NREG; ++r) v[r] = packkey(pl[r], ph[r]);

  // ---- initial 16-element intra-reg sort: Batcher OEM (63 CEs) ----
  oem_sort<0, 16>(v);

  // ---- cross-lane bitonic merge stages (i = half*1024 + lane*16 + reg) ----
  lanerev<1, 1>(v, lane, a63);  REGX4;                     // K=32
  lanerev<3, 2>(v, lane, a63);  lanex<1>(v, lane, a63); REGX4;                          // K=64
  lanerev<7, 4>(v, lane, a63);  lanex<2>(v, lane, a63); lanex<1>(v, lane, a63); REGX4;  // K=128
  lanerev<15, 8>(v, lane, a63); lanex4(v, lane); lanex<2>(v, lane, a63);
  lanex<1>(v, lane, a63); REGX4;                           // K=256
  lanerev<31, 16>(v, lane, a63); lanex<8>(v, lane, a63); lanex4(v, lane);
  lanex<2>(v, lane, a63); lanex<1>(v, lane, a63); REGX4;   // K=512
  lanerev<63, 32>(v, lane, a63); lanepair<16>(v, lane); lanex<8>(v, lane, a63);
  lanex4(v, lane); lanex<2>(v, lane, a63); lanex<1>(v, lane, a63); REGX4;  // K=1024 (per half)
  halfrev(v, a63, hm); lanepair<32>(v, lane); lanepair<16>(v, lane);
  lanex<8>(v, lane, a63); lanex4(v, lane); lanex<2>(v, lane, a63);
  lanex<1>(v, lane, a63); REGX4;                           // K=2048

  // ---- join: wave 1 publishes sorted Q as f32, wave 0 computes SSD ----
  if (wid == 1) {
#pragma unroll
    for (int r = 0; r < NREG; ++r) {
      float lo, hi;
      unpackkey(v[r], lo, hi);
      sj[lane * 33 + r] = lo;
      sj[lane * 33 + 16 + r] = hi;
    }
  }
  __syncthreads();
  if (wid == 0) {
    float acc = 0.f;
#pragma unroll
    for (int r = 0; r < NREG; ++r) {
      float lo, hi;
      unpackkey(v[r], lo, hi);
      const float dl = lo - sj[lane * 33 + r];
      const float dh = hi - sj[lane * 33 + 16 + r];
      acc += dl * dl + dh * dh;
    }
#pragma unroll
    for (int off = 32; off > 0; off >>= 1) acc += __shfl_down(acc, off, 64);
    if (lane == 0) partial[pair] = acc;
  }
}

// Single block: per-batch reduce over L partials, sqrt, mean over B.
__global__ __launch_bounds__(BATCH) void swd_finalize_kernel(
    const float* __restrict__ partial, float* __restrict__ out) {
  const int b = threadIdx.x;  // 0..127
  float s = 0.f;
  for (int l = 0; l < NPROJ; ++l) s += partial[b * NPROJ + l];
  float swd = sqrtf(s / (float)(NPTS * NPROJ));
  for (int off = 32; off > 0; off >>= 1) swd += __shfl_down(swd, off, 64);
  __shared__ float wsum[BATCH / 64];
  if ((threadIdx.x & 63) == 0) wsum[threadIdx.x >> 6] = swd;
  __syncthreads();
  if (threadIdx.x == 0) out[0] = (wsum[0] + wsum[1]) / (float)BATCH;
}

extern "C" void kernel_launch(void* const* d_in, const int* in_sizes, int n_in,
                              void* d_out, int out_size, void* d_ws, size_t ws_size,
                              hipStream_t stream) {
  const float* P    = (const float*)d_in[0];
  const float* Q    = (const float*)d_in[1];
  const float* proj = (const float*)d_in[2];
  float* out = (float*)d_out;
  float* partial = (float*)d_ws;  // BATCH*NPROJ floats = 51.2 KB

  swd_sort_kernel<<<BATCH * NPROJ, NTH, 0, stream>>>(P, Q, proj, partial);
  swd_finalize_kernel<<<1, BATCH, 0, stream>>>(partial, out);
}

// Round 18
// 107.719 us; speedup vs baseline: 1.0434x; 1.0434x over previous
//
#include <hip/hip_runtime.h>
#include <hip/hip_bf16.h>
#include <hip/hip_fp16.h>

#define BATCH 128
#define NPTS  2048
#define NDIM  3
#define NPROJ 100
#define NTH   128   // 2 waves per block: wave 0 sorts P, wave 1 sorts Q
#define NREG  16    // 16 packed regs = 32 x 16-bit keys per thread

typedef unsigned int u32;
typedef _Float16 h2_t __attribute__((ext_vector_type(2)));
typedef unsigned short u16x2 __attribute__((ext_vector_type(2)));

// Packed 2x16-bit unsigned min/max -> v_pk_min_u16 / v_pk_max_u16.
__device__ __forceinline__ u32 pmin(u32 a, u32 b) {
#if __has_builtin(__builtin_elementwise_min)
  return __builtin_bit_cast(u32, __builtin_elementwise_min(
      __builtin_bit_cast(u16x2, a), __builtin_bit_cast(u16x2, b)));
#else
  u32 d; asm("v_pk_min_u16 %0, %1, %2" : "=v"(d) : "v"(a), "v"(b)); return d;
#endif
}
__device__ __forceinline__ u32 pmax(u32 a, u32 b) {
#if __has_builtin(__builtin_elementwise_max)
  return __builtin_bit_cast(u32, __builtin_elementwise_max(
      __builtin_bit_cast(u16x2, a), __builtin_bit_cast(u16x2, b)));
#else
  u32 d; asm("v_pk_max_u16 %0, %1, %2" : "=v"(d) : "v"(a), "v"(b)); return d;
#endif
}

// Pack two f32 -> one u32 of two order-preserving f16 keys (RTZ, monotone).
__device__ __forceinline__ u32 packkey(float lo, float hi) {
  const u32 h2 = __builtin_bit_cast(u32, __builtin_amdgcn_cvt_pkrtz(lo, hi));
  const u32 t = (h2 & 0x80008000u) >> 15;
  return h2 ^ ((t * 0x7FFFu) | 0x80008000u);
}
// Inverse: packed key -> two f32.
__device__ __forceinline__ void unpackkey(u32 k, float& lo, float& hi) {
  const u32 t = ((~k) & 0x80008000u) >> 15;
  const u32 h2 = k ^ ((t * 0x7FFFu) | 0x80008000u);
  const h2_t h = __builtin_bit_cast(h2_t, h2);
  lo = (float)h.x;
  hi = (float)h.y;
}

// Cross-lane xor shuffle: DPP where an exact form exists (VALU), else DS.
// This split (4/31 on DS, rest DPP) is the measured two-pipe Pareto point:
// R17's A/B showed moving mask-4 to DPP costs 4% (VALU is the binding pipe).
template<int M>
__device__ __forceinline__ u32 shuf(u32 v, int a63) {
  const int x = (int)v;
  int r;
  if constexpr (M == 1)       r = __builtin_amdgcn_mov_dpp(x, 0xB1, 0xF, 0xF, true);   // quad [1,0,3,2]
  else if constexpr (M == 2)  r = __builtin_amdgcn_mov_dpp(x, 0x4E, 0xF, 0xF, true);   // quad [2,3,0,1]
  else if constexpr (M == 3)  r = __builtin_amdgcn_mov_dpp(x, 0x1B, 0xF, 0xF, true);   // quad [3,2,1,0]
  else if constexpr (M == 7)  r = __builtin_amdgcn_mov_dpp(x, 0x141, 0xF, 0xF, true);  // row_half_mirror
  else if constexpr (M == 8)  r = __builtin_amdgcn_mov_dpp(x, 0x128, 0xF, 0xF, true);  // row_ror:8
  else if constexpr (M == 15) r = __builtin_amdgcn_mov_dpp(x, 0x140, 0xF, 0xF, true);  // row_mirror
  else if constexpr (M == 63) r = __builtin_amdgcn_ds_bpermute(a63, x);
  else                        r = __builtin_amdgcn_ds_swizzle(x, (M << 10) | 0x1F);    // 4, 31
  return (u32)r;
}

// Compare-exchange on two packed regs (min to first).
__device__ __forceinline__ void ce(u32& a, u32& b) {
  const u32 mn = pmin(a, b), mx = pmax(a, b);
  a = mn;
  b = mx;
}

// Batcher odd-even mergesort over the 16 regs (63 CEs); compile-time indices.
template<int I, int R, int END, int M>
__device__ __forceinline__ void oem_chain(u32 v[NREG]) {
  if constexpr (I + R < END) {
    ce(v[I], v[I + R]);
    oem_chain<I + M, R, END, M>(v);
  }
}
template<int LO, int R, int N>
__device__ __forceinline__ void oem_merge(u32 v[NREG]) {
  constexpr int M = R * 2;
  if constexpr (M < N) {
    oem_merge<LO, M, N>(v);
    oem_merge<LO + R, M, N>(v);
    oem_chain<LO + R, R, LO + N, M>(v);
  } else {
    ce(v[LO], v[LO + R]);
  }
}
template<int LO, int N>
__device__ __forceinline__ void oem_sort(u32 v[NREG]) {
  if constexpr (N > 1) {
    constexpr int M = N / 2;
    oem_sort<LO, M>(v);
    oem_sort<LO + M, M>(v);
    oem_merge<LO, 1, N>(v);
  }
}

// Reg-bit xor CE (bitonic merge substep, uniform direction).
template<int J>
__device__ __forceinline__ void regx(u32 v[NREG]) {
#pragma unroll
  for (int s = 0; s < NREG; ++s) {
    if ((s & J) == 0) {
      const u32 a = v[s], b = v[s | J];
      v[s] = pmin(a, b);
      v[s | J] = pmax(a, b);
    }
  }
}

// Lane-space reversal CE: partner lane^M, regs reversed; lane&HB==0 keeps min.
template<int M, int HB>
__device__ __forceinline__ void lanerev(u32 v[NREG], const int lane, const int a63) {
  u32 o[NREG];
#pragma unroll
  for (int r = 0; r < NREG; ++r) o[r] = shuf<M>(v[NREG - 1 - r], a63);
  if (lane & HB) {
#pragma unroll
    for (int r = 0; r < NREG; ++r) v[r] = pmax(v[r], o[r]);
  } else {
#pragma unroll
    for (int r = 0; r < NREG; ++r) v[r] = pmin(v[r], o[r]);
  }
}

// Lane-space xor CE at lane mask M (exact shuffles).
template<int M>
__device__ __forceinline__ void lanex(u32 v[NREG], const int lane, const int a63) {
  u32 o[NREG];
#pragma unroll
  for (int r = 0; r < NREG; ++r) o[r] = shuf<M>(v[r], a63);
  if (lane & M) {
#pragma unroll
    for (int r = 0; r < NREG; ++r) v[r] = pmax(v[r], o[r]);
  } else {
#pragma unroll
    for (int r = 0; r < NREG; ++r) v[r] = pmin(v[r], o[r]);
  }
}

// Lane-space xor CE at mask 16/32 via permlane swap (unordered pair, VALU).
template<int HB>
__device__ __forceinline__ void lanepair(u32 v[NREG], const int lane) {
  u32 a[NREG], o[NREG];
#pragma unroll
  for (int r = 0; r < NREG; ++r) {
    if constexpr (HB == 16) {
#if __has_builtin(__builtin_amdgcn_permlane16_swap)
      auto p = __builtin_amdgcn_permlane16_swap((int)v[r], (int)v[r], false, false);
      a[r] = (u32)p[0]; o[r] = (u32)p[1];
#else
      a[r] = v[r];
      o[r] = (u32)__builtin_amdgcn_ds_swizzle((int)v[r], (16 << 10) | 0x1F);
#endif
    } else {
#if __has_builtin(__builtin_amdgcn_permlane32_swap)
      auto p = __builtin_amdgcn_permlane32_swap((int)v[r], (int)v[r], false, false);
      a[r] = (u32)p[0]; o[r] = (u32)p[1];
#else
      a[r] = v[r];
      o[r] = (u32)__builtin_amdgcn_ds_bpermute(((lane ^ 32) << 2), (int)v[r]);
#endif
    }
  }
  if (lane & HB) {
#pragma unroll
    for (int r = 0; r < NREG; ++r) v[r] = pmax(a[r], o[r]);
  } else {
#pragma unroll
    for (int r = 0; r < NREG; ++r) v[r] = pmin(a[r], o[r]);
  }
}

// K=2048 reversal: flips half bit + lane^63 + reg reversal; partner arrives
// half-swapped (alignbit rotate 16); lo half keeps min, hi keeps max.
__device__ __forceinline__ void halfrev(u32 v[NREG], const int a63, const u32 hm) {
  u32 o[NREG];
#pragma unroll
  for (int r = 0; r < NREG; ++r) o[r] = shuf<63>(v[NREG - 1 - r], a63);
#pragma unroll
  for (int r = 0; r < NREG; ++r) {
    u32 osw;
    asm("v_alignbit_b32 %0, %1, %1, 16" : "=v"(osw) : "v"(o[r]));
    const u32 t1 = pmin(v[r], osw);
    const u32 t2 = pmax(v[r], osw);
    asm("v_bfi_b32 %0, %1, %2, %3" : "=v"(v[r]) : "v"(hm), "v"(t2), "v"(t1));
  }
}

#define REGX4 regx<8>(v); regx<4>(v); regx<2>(v); regx<1>(v)

// ---------------------------------------------------------------------------
// One 128-thread block per (b, l). Wave 0: P, wave 1: Q. 2048 f16 keys per
// wave packed 2-per-register; XCD-bijective swizzle for L2 reuse.
// Final configuration (R15): 656 us (R1 LDS bitonic) -> 108 us via
// register sort + uint keys + packed f16 + pipe balance + XCD swizzle.
// ---------------------------------------------------------------------------
__global__ __launch_bounds__(NTH) void swd_sort_kernel(
    const float* __restrict__ P, const float* __restrict__ Q,
    const float* __restrict__ proj, float* __restrict__ partial) {
  __shared__ float sj[64 * 33];
  // 12800 blocks, 8 XCDs, 12800%8==0: xcd = bid%8 owns pairs [xcd*1600, ..)
  const int pair = (blockIdx.x & 7) * (BATCH * NPROJ / 8) + (blockIdx.x >> 3);
  const int b = pair / NPROJ;
  const int l = pair - b * NPROJ;
  const int wid  = threadIdx.x >> 6;
  const int lane = threadIdx.x & 63;
  const int a63 = ((lane ^ 63) << 2);
  const u32 hm = 0xFFFF0000u;

  const float d0 = proj[b * NDIM * NPROJ + l];
  const float d1 = proj[b * NDIM * NPROJ + NPROJ + l];
  const float d2 = proj[b * NDIM * NPROJ + 2 * NPROJ + l];

  const float* __restrict__ src = wid ? Q : P;
  const float4* base = reinterpret_cast<const float4*>(src + (size_t)b * NPTS * NDIM);
  const float4* SA = base + lane * 12;        // points lane*16 .. +15  (half 0)
  const float4* SB = base + 768 + lane * 12;  // points 1024+lane*16 ..(half 1)

  float pl[NREG], ph[NREG];
#pragma unroll
  for (int c = 0; c < 4; ++c) {  // 3 float4 = 4 points
    const float4 x = SA[c * 3 + 0], y = SA[c * 3 + 1], z = SA[c * 3 + 2];
    pl[c * 4 + 0] = x.x * d0 + x.y * d1 + x.z * d2;
    pl[c * 4 + 1] = x.w * d0 + y.x * d1 + y.y * d2;
    pl[c * 4 + 2] = y.z * d0 + y.w * d1 + z.x * d2;
    pl[c * 4 + 3] = z.y * d0 + z.z * d1 + z.w * d2;
  }
#pragma unroll
  for (int c = 0; c < 4; ++c) {
    const float4 x = SB[c * 3 + 0], y = SB[c * 3 + 1], z = SB[c * 3 + 2];
    ph[c * 4 + 0] = x.x * d0 + x.y * d1 + x.z * d2;
    ph[c * 4 + 1] = x.w * d0 + y.x * d1 + y.y * d2;
    ph[c * 4 + 2] = y.z * d0 + y.w * d1 + z.x * d2;
    ph[c * 4 + 3] = z.y * d0 + z.z * d1 + z.w * d2;
  }

  u32 v[NREG];
#pragma unroll
  for (int r = 0; r < NREG; ++r) v[r] = packkey(pl[r], ph[r]);

  // ---- initial 16-element intra-reg sort: Batcher OEM (63 CEs) ----
  oem_sort<0, 16>(v);

  // ---- cross-lane bitonic merge stages (i = half*1024 + lane*16 + reg) ----
  lanerev<1, 1>(v, lane, a63);  REGX4;                     // K=32
  lanerev<3, 2>(v, lane, a63);  lanex<1>(v, lane, a63); REGX4;                          // K=64
  lanerev<7, 4>(v, lane, a63);  lanex<2>(v, lane, a63); lanex<1>(v, lane, a63); REGX4;  // K=128
  lanerev<15, 8>(v, lane, a63); lanex<4>(v, lane, a63); lanex<2>(v, lane, a63);
  lanex<1>(v, lane, a63); REGX4;                           // K=256
  lanerev<31, 16>(v, lane, a63); lanex<8>(v, lane, a63); lanex<4>(v, lane, a63);
  lanex<2>(v, lane, a63); lanex<1>(v, lane, a63); REGX4;   // K=512
  lanerev<63, 32>(v, lane, a63); lanepair<16>(v, lane); lanex<8>(v, lane, a63);
  lanex<4>(v, lane, a63); lanex<2>(v, lane, a63); lanex<1>(v, lane, a63); REGX4;  // K=1024 (per half)
  halfrev(v, a63, hm); lanepair<32>(v, lane); lanepair<16>(v, lane);
  lanex<8>(v, lane, a63); lanex<4>(v, lane, a63); lanex<2>(v, lane, a63);
  lanex<1>(v, lane, a63); REGX4;                           // K=2048

  // ---- join: wave 1 publishes sorted Q as f32, wave 0 computes SSD ----
  if (wid == 1) {
#pragma unroll
    for (int r = 0; r < NREG; ++r) {
      float lo, hi;
      unpackkey(v[r], lo, hi);
      sj[lane * 33 + r] = lo;
      sj[lane * 33 + 16 + r] = hi;
    }
  }
  __syncthreads();
  if (wid == 0) {
    float acc = 0.f;
#pragma unroll
    for (int r = 0; r < NREG; ++r) {
      float lo, hi;
      unpackkey(v[r], lo, hi);
      const float dl = lo - sj[lane * 33 + r];
      const float dh = hi - sj[lane * 33 + 16 + r];
      acc += dl * dl + dh * dh;
    }
#pragma unroll
    for (int off = 32; off > 0; off >>= 1) acc += __shfl_down(acc, off, 64);
    if (lane == 0) partial[pair] = acc;
  }
}

// Single block: per-batch reduce over L partials, sqrt, mean over B.
__global__ __launch_bounds__(BATCH) void swd_finalize_kernel(
    const float* __restrict__ partial, float* __restrict__ out) {
  const int b = threadIdx.x;  // 0..127
  float s = 0.f;
  for (int l = 0; l < NPROJ; ++l) s += partial[b * NPROJ + l];
  float swd = sqrtf(s / (float)(NPTS * NPROJ));
  for (int off = 32; off > 0; off >>= 1) swd += __shfl_down(swd, off, 64);
  __shared__ float wsum[BATCH / 64];
  if ((threadIdx.x & 63) == 0) wsum[threadIdx.x >> 6] = swd;
  __syncthreads();
  if (threadIdx.x == 0) out[0] = (wsum[0] + wsum[1]) / (float)BATCH;
}

extern "C" void kernel_launch(void* const* d_in, const int* in_sizes, int n_in,
                              void* d_out, int out_size, void* d_ws, size_t ws_size,
                              hipStream_t stream) {
  const float* P    = (const float*)d_in[0];
  const float* Q    = (const float*)d_in[1];
  const float* proj = (const float*)d_in[2];
  float* out = (float*)d_out;
  float* partial = (float*)d_ws;  // BATCH*NPROJ floats = 51.2 KB

  swd_sort_kernel<<<BATCH * NPROJ, NTH, 0, stream>>>(P, Q, proj, partial);
  swd_finalize_kernel<<<1, BATCH, 0, stream>>>(partial, out);
}